// Round 18
// baseline (1330.363 us; speedup 1.0000x reference)
//
#include <hip/hip_runtime.h>

#define BATCH 8
#define SEQ   4096
#define DM    256
#define DI    512
#define DS    16
#define DTR   16
#define NL    6
#define MROWS (BATCH*SEQ)   // 32768
#define CCH   256           // scan chunks
#define CL    (SEQ/CCH)     // 16 steps per chunk
#define SC    (BATCH*DI*DS) // 65536 per-chunk scan states

typedef float  f32x4 __attribute__((ext_vector_type(4)));
typedef float  f32x2 __attribute__((ext_vector_type(2)));
typedef __bf16 bf16x8 __attribute__((ext_vector_type(8)));
typedef unsigned short u16x8 __attribute__((ext_vector_type(8)));
typedef unsigned short u16x4 __attribute__((ext_vector_type(4)));

__device__ __forceinline__ float bf2f(unsigned short b){
  unsigned u = ((unsigned)b) << 16;
  return __builtin_bit_cast(float, u);
}
__device__ __forceinline__ unsigned short f2bf(float f){
  unsigned u = __builtin_bit_cast(unsigned, f);
  unsigned r = u + 0x7FFFu + ((u >> 16) & 1u);
  return (unsigned short)(r >> 16);
}

#define ASEL(i) ((i)<4?Aq0[(i)&3]:(i)<8?Aq1[(i)&3]:(i)<12?Aq2[(i)&3]:Aq3[(i)&3])

// packed powers: ap2[j] = {a1^(2j+1), a1^(2j+2)}, j=0..7  (3 scalar + 7 pk muls)
__device__ __forceinline__ void powers16_pk(float a1, f32x2* ap2){
  float a2=a1*a1, a4=a2*a2, a8=a4*a4;
  ap2[0] = f32x2{a1, a2};
  ap2[1] = ap2[0]*a2;   // a3,a4
  ap2[2] = ap2[0]*a4;   // a5,a6
  ap2[3] = ap2[1]*a4;   // a7,a8
  ap2[4] = ap2[0]*a8;   // a9,a10
  ap2[5] = ap2[1]*a8;   // a11,a12
  ap2[6] = ap2[2]*a8;   // a13,a14
  ap2[7] = ap2[3]*a8;   // a15,a16
}

// ---------------- transpose x [B,256,L] f32 -> h [(b*L+l)*256+c] bf16 ----------------
__global__ void transpose_in(const float* __restrict__ x, unsigned short* __restrict__ h){
  __shared__ float tile[32][33];
  int b = blockIdx.z;
  int l0 = blockIdx.x*32, c0 = blockIdx.y*32;
  int tx = threadIdx.x, ty = threadIdx.y;
  #pragma unroll
  for (int i=0;i<4;i++)
    tile[ty+8*i][tx] = x[((size_t)(b*DM + c0+ty+8*i))*SEQ + l0 + tx];
  __syncthreads();
  #pragma unroll
  for (int i=0;i<4;i++)
    h[((size_t)(b*SEQ + l0+ty+8*i))*DM + c0 + tx] = f2bf(tile[tx][ty+8*i]);
}

// ---------------- transpose h (bf16) -> out [B,256,L] f32 ----------------
__global__ void transpose_out(const unsigned short* __restrict__ h, float* __restrict__ out){
  __shared__ float tile[32][33];
  int b = blockIdx.z;
  int l0 = blockIdx.x*32, c0 = blockIdx.y*32;
  int tx = threadIdx.x, ty = threadIdx.y;
  #pragma unroll
  for (int i=0;i<4;i++)
    tile[ty+8*i][tx] = bf2f(h[((size_t)(b*SEQ + l0+ty+8*i))*DM + c0 + tx]);
  __syncthreads();
  #pragma unroll
  for (int i=0;i<4;i++)
    out[((size_t)(b*DM + c0+ty+8*i))*SEQ + l0 + tx] = tile[tx][ty+8*i];
}

// ---------------- f32 -> bf16 convert ----------------
__global__ void cvt_bf16(const float* __restrict__ in, unsigned short* __restrict__ out, int n){
  int i = blockIdx.x*256 + threadIdx.x;
  if (i < n) out[i] = f2bf(in[i]);
}

// ------- W_dt padded to K=32 (cols 16..31 zero), bf16: Wdtp[l][512][32] -------
__global__ void wdtp_kernel(const float* __restrict__ Wdt, unsigned short* __restrict__ Wdtp){
  int idx = blockIdx.x*256 + threadIdx.x;   // over NL*512*32
  int l = idx >> 14;
  int r = idx & 16383;
  int d = r >> 5, k = r & 31;
  float v = (k < 16) ? Wdt[(size_t)l*DI*DTR + d*DTR + k] : 0.f;
  Wdtp[idx] = f2bf(v);
}

// ---------------- LayerNorm over 256 channels, one wave per row, bf16 in/out ----------------
__global__ void ln_kernel(const unsigned short* __restrict__ h, const float* __restrict__ g,
                          const float* __restrict__ bta, unsigned short* __restrict__ out){
  int wave = threadIdx.x >> 6, lane = threadIdx.x & 63;
  size_t row = (size_t)blockIdx.x*4 + wave;
  u16x4 hv = *reinterpret_cast<const u16x4*>(h + row*DM + lane*4);
  float v0 = bf2f(hv[0]), v1 = bf2f(hv[1]), v2 = bf2f(hv[2]), v3 = bf2f(hv[3]);
  float s  = v0 + v1 + v2 + v3;
  float sq = v0*v0 + v1*v1 + v2*v2 + v3*v3;
  #pragma unroll
  for (int off=32; off; off>>=1){
    s  += __shfl_xor(s,  off, 64);
    sq += __shfl_xor(sq, off, 64);
  }
  float mean = s * (1.f/DM);
  float var  = sq * (1.f/DM) - mean*mean;
  float rstd = rsqrtf(var + 1e-5f);
  f32x4 gg = *reinterpret_cast<const f32x4*>(g   + lane*4);
  f32x4 bb = *reinterpret_cast<const f32x4*>(bta + lane*4);
  unsigned short* o = out + row*DM + lane*4;
  u16x4 ov;
  ov[0] = f2bf((v0-mean)*rstd*gg.x + bb.x);
  ov[1] = f2bf((v1-mean)*rstd*gg.y + bb.y);
  ov[2] = f2bf((v2-mean)*rstd*gg.z + bb.z);
  ov[3] = f2bf((v3-mean)*rstd*gg.w + bb.w);
  *reinterpret_cast<u16x4*>(o) = ov;
}

// ======== 256x128-tile LDS double-buffered bf16 MFMA GEMM, 8 waves (64x64/wave) ========
// C[M,N] = A[M,K] @ W[N,K]^T. BK=32, dbuf, 2-barrier schedule. T1 XCD remap.
// MFMA operands SWAPPED (mfma(B,A)) so each lane's f32x4 = 4 consecutive N-cols of one
// row -> u16x4 / f32x4 vector stores in all epilogues.
// OUTMODE 1: bf16 store, silu for col >= N/2 (xz projection).
// OUTMODE 2: bf16 RMW accumulate (residual).
// OUTMODE 3: softplus(acc + bias[col]) bf16 store (delta; N==512, K==32).
// OUTMODE 5: split48 — col<16: bf16 dt -> Cout[row*32+col]; 16..31: f32 B -> Cout2 + zero-pad
//            Cout; 32..47: f32 C -> Cout2.
template<int OUTMODE>
__global__ __launch_bounds__(512) void gemm_big(const unsigned short* __restrict__ A,
                                                const unsigned short* __restrict__ W,
                                                void* __restrict__ Cout,
                                                float* __restrict__ Cout2,
                                                const float* __restrict__ bias, int N, int K){
  __shared__ __align__(16) unsigned short lds[2][12288];  // A: [0,8192) B: [8192,12288)
  unsigned nx = gridDim.x;
  unsigned L = blockIdx.x + nx*blockIdx.y;
  unsigned nwg = nx * gridDim.y;
  unsigned wid = (L & 7u) * (nwg >> 3) + (L >> 3);
  int bx = wid % nx, by = wid / nx;

  int tid  = threadIdx.x;
  int wave = tid >> 6, lane = tid & 63;
  int wr = wave >> 1, wc = wave & 1;
  int mblock = by*256, nblock = bx*128;
  int l15 = lane & 15;
  int g = lane >> 4;
  int rr = lane >> 2;
  int scol = ((lane&3) ^ (rr&3) ^ ((rr>>2)&3)) * 8;
  int rs = (g ^ (l15&3) ^ ((l15>>2)&3)) * 8;

  f32x4 acc[4][4] = {};

  auto stage = [&](int buf, int k0){
    #pragma unroll
    for (int j=0; j<2; j++){
      int st = wave*2 + j;                       // A stripes 0..15
      int rA = mblock + st*16 + rr;
      const unsigned short* ga = A + (size_t)rA*K + k0 + scol;
      __builtin_amdgcn_global_load_lds(ga, &lds[buf][st*512], 16, 0, 0);
    }
    {
      int st = wave;                             // B stripes 0..7
      int rB = nblock + st*16 + rr; if (rB >= N) rB = N-1;
      const unsigned short* gb = W + (size_t)rB*K + k0 + scol;
      __builtin_amdgcn_global_load_lds(gb, &lds[buf][8192 + st*512], 16, 0, 0);
    }
  };

  stage(0, 0);
  __syncthreads();

  int nsteps = K >> 5;
  for (int s=0; s<nsteps; s++){
    int buf = s & 1;
    if (s+1 < nsteps) stage(buf^1, (s+1)*32);
    bf16x8 af[4], bfr[4];
    #pragma unroll
    for (int mf=0; mf<4; mf++)
      af[mf] = *(const bf16x8*)&lds[buf][(wr*64 + mf*16 + l15)*32 + rs];
    #pragma unroll
    for (int nf=0; nf<4; nf++)
      bfr[nf] = *(const bf16x8*)&lds[buf][8192 + (wc*64 + nf*16 + l15)*32 + rs];
    #pragma unroll
    for (int mf=0; mf<4; mf++)
      #pragma unroll
      for (int nf=0; nf<4; nf++)
        acc[mf][nf] = __builtin_amdgcn_mfma_f32_16x16x32_bf16(bfr[nf], af[mf], acc[mf][nf], 0,0,0);
    __syncthreads();
  }

  // transposed-C epilogue: lane holds row = ...+l15, cols = ...+g*4+{0..3}
  int rowb = mblock + wr*64 + l15;
  int colb = nblock + wc*64 + g*4;
  #pragma unroll
  for (int mf=0; mf<4; mf++){
    int row = rowb + mf*16;
    #pragma unroll
    for (int nf=0; nf<4; nf++){
      int col = colb + nf*16;
      f32x4 v = acc[mf][nf];
      if (OUTMODE == 1){
        if (col >= (N>>1)){
          v.x = v.x / (1.f + __expf(-v.x)); v.y = v.y / (1.f + __expf(-v.y));
          v.z = v.z / (1.f + __expf(-v.z)); v.w = v.w / (1.f + __expf(-v.w));
        }
        u16x4 pk = {f2bf(v.x), f2bf(v.y), f2bf(v.z), f2bf(v.w)};
        *(u16x4*)((unsigned short*)Cout + (size_t)row*N + col) = pk;
      } else if (OUTMODE == 2){
        unsigned short* hp = (unsigned short*)Cout + (size_t)row*N + col;
        u16x4 old = *(const u16x4*)hp;
        u16x4 pk = {f2bf(bf2f(old[0]) + v.x), f2bf(bf2f(old[1]) + v.y),
                    f2bf(bf2f(old[2]) + v.z), f2bf(bf2f(old[3]) + v.w)};
        *(u16x4*)hp = pk;
      } else if (OUTMODE == 3){
        f32x4 b4 = *(const f32x4*)(bias + col);
        f32x4 t = v + b4;
        u16x4 pk;
        pk[0] = f2bf(fmaxf(t.x,0.f) + __logf(1.f + __expf(-fabsf(t.x))));
        pk[1] = f2bf(fmaxf(t.y,0.f) + __logf(1.f + __expf(-fabsf(t.y))));
        pk[2] = f2bf(fmaxf(t.z,0.f) + __logf(1.f + __expf(-fabsf(t.z))));
        pk[3] = f2bf(fmaxf(t.w,0.f) + __logf(1.f + __expf(-fabsf(t.w))));
        *(u16x4*)((unsigned short*)Cout + (size_t)row*N + col) = pk;
      } else { // OUTMODE 5
        if (col < 16){
          u16x4 pk = {f2bf(v.x), f2bf(v.y), f2bf(v.z), f2bf(v.w)};
          *(u16x4*)((unsigned short*)Cout + (size_t)row*32 + col) = pk;
        } else if (col < 48){
          *(f32x4*)(Cout2 + (size_t)row*32 + (col - 16)) = v;
          if (col < 32){
            u16x4 z = {0,0,0,0};
            *(u16x4*)((unsigned short*)Cout + (size_t)row*32 + col) = z;  // zero K-pad
          }
        }
      }
    }
  }
}

// ---------------- depthwise causal conv(4) + bias + SiLU, 8 channels x 2 rows/thread ----------------
__global__ void conv_kernel(const unsigned short* __restrict__ xz, const float* __restrict__ cw,
                            const float* __restrict__ cb, unsigned short* __restrict__ u){
  size_t idx = (size_t)blockIdx.x*256 + threadIdx.x;  // over MROWS/2 * 64
  int d0 = (int)(idx & 63) * 8;
  size_t row = (idx >> 6) * 2;
  int l = (int)(row & (SEQ-1));
  const unsigned short* base = xz + row*1024 + d0;
  u16x8 x0 = (l>=3) ? *(const u16x8*)(base - 3072) : (u16x8)(0);  // row-3
  u16x8 x1 = (l>=2) ? *(const u16x8*)(base - 2048) : (u16x8)(0);  // row-2
  u16x8 x2 = (l>=1) ? *(const u16x8*)(base - 1024) : (u16x8)(0);  // row-1
  u16x8 x3 = *(const u16x8*)(base);                               // row
  u16x8 x4 = *(const u16x8*)(base + 1024);                        // row+1 (same batch: row even)
  f32x4 cb0 = *reinterpret_cast<const f32x4*>(cb + d0);
  f32x4 cb1 = *reinterpret_cast<const f32x4*>(cb + d0 + 4);
  u16x8 o0, o1;
  #pragma unroll
  for (int j=0; j<8; j++){
    f32x4 w = *reinterpret_cast<const f32x4*>(cw + (d0+j)*4);
    float bj = (j<4) ? cb0[j] : cb1[j-4];
    float a0 = bj + bf2f(x0[j])*w.x + bf2f(x1[j])*w.y + bf2f(x2[j])*w.z + bf2f(x3[j])*w.w;
    float a1 = bj + bf2f(x1[j])*w.x + bf2f(x2[j])*w.y + bf2f(x3[j])*w.z + bf2f(x4[j])*w.w;
    o0[j] = f2bf(a0 / (1.f + __expf(-a0)));
    o1[j] = f2bf(a1 / (1.f + __expf(-a1)));
  }
  *(u16x8*)(u + row*512 + d0)       = o0;
  *(u16x8*)(u + (row+1)*512 + d0)   = o1;
}

// ================= SSM chunked scan, lane-per-d layout, packed f32x2 math =================
// B/C staged in LDS: Bls[l*32 + 0..15] = B, [16..31] = C
template<bool POW>
__device__ __forceinline__ void pass1_body(
    const unsigned short* dptr, const unsigned short* uptr, const float* Bls,
    const float* A, f32x2* h2, float& sumdv){
  #pragma unroll 2
  for (int l=0; l<CL; l++){
    float dv = bf2f(dptr[(size_t)l*512]);
    float uv = bf2f(uptr[(size_t)l*512]);
    const float* br = Bls + l*32;
    f32x4 B0 = *(const f32x4*)(br + 0);
    f32x4 B1 = *(const f32x4*)(br + 4);
    f32x4 B2 = *(const f32x4*)(br + 8);
    f32x4 B3 = *(const f32x4*)(br + 12);
    f32x2 b2[8] = {B0.xy, B0.zw, B1.xy, B1.zw, B2.xy, B2.zw, B3.xy, B3.zw};
    float t = dv*uv;
    sumdv += dv;
    if (POW){
      f32x2 ap2[8];
      powers16_pk(__expf(dv*A[0]), ap2);
      #pragma unroll
      for (int j=0;j<8;j++){ h2[j] = ap2[j]*h2[j] + t*b2[j]; }
    } else {
      #pragma unroll
      for (int j=0;j<8;j++){
        f32x2 a = f32x2{__expf(dv*A[2*j]), __expf(dv*A[2*j+1])};
        h2[j] = a*h2[j] + t*b2[j];
      }
    }
  }
}

__global__ void __launch_bounds__(256) scan_pass1(
    const unsigned short* __restrict__ dlt, const unsigned short* __restrict__ u,
    const float* __restrict__ xdb, const float* __restrict__ Alog,
    float* __restrict__ sumdvB, unsigned short* __restrict__ Hbuf){
  __shared__ float Bls[CL*32];
  int bid = blockIdx.x;               // ((b*CCH)+c)*2 + half
  int half = bid & 1;
  int c = (bid >> 1) & (CCH-1);
  int b = bid / (CCH*2);
  int wave = threadIdx.x >> 6, lane = threadIdx.x & 63;
  int d = half*256 + wave*64 + lane;
  size_t rowbase = (size_t)b*SEQ + (size_t)c*CL;
  // stage B/C: 16 rows x 32 f32 = 2KB, f32x2 per thread
  *(f32x2*)&Bls[threadIdx.x*2] = *(const f32x2*)(xdb + rowbase*32 + threadIdx.x*2);
  const float* ar = Alog + d*16;
  f32x4 Aq0 = *(const f32x4*)(ar+0), Aq1 = *(const f32x4*)(ar+4);
  f32x4 Aq2 = *(const f32x4*)(ar+8), Aq3 = *(const f32x4*)(ar+12);
  float A[16];
  #pragma unroll
  for (int i=0;i<16;i++) A[i] = -__expf(ASEL(i));
  bool pw = true;
  #pragma unroll
  for (int i=1;i<16;i++) pw = pw && (fabsf(A[i] - (float)(i+1)*A[0]) <= 1e-3f*fabsf(A[i]));
  f32x2 h2[8];
  #pragma unroll
  for (int j=0;j<8;j++) h2[j] = f32x2{0.f,0.f};
  float sumdv = 0.f;
  const unsigned short* dptr = dlt + rowbase*512 + d;
  const unsigned short* uptr = u   + rowbase*512 + d;
  __syncthreads();
  if (pw) pass1_body<true >(dptr, uptr, Bls, A, h2, sumdv);
  else    pass1_body<false>(dptr, uptr, Bls, A, h2, sumdv);
  size_t o = (size_t)(c*BATCH + b)*512 + d;
  sumdvB[o] = sumdv;
  unsigned short* Hp = Hbuf + o*16;
  u16x8 ha, hb;
  #pragma unroll
  for (int j=0;j<4;j++){ ha[2*j] = f2bf(h2[j].x); ha[2*j+1] = f2bf(h2[j].y); }
  #pragma unroll
  for (int j=0;j<4;j++){ hb[2*j] = f2bf(h2[4+j].x); hb[2*j+1] = f2bf(h2[4+j].y); }
  *(u16x8*)(Hp+0) = ha;
  *(u16x8*)(Hp+8) = hb;
}

// pass2: thread per (b,d,n): serial combine over chunks; Hbuf[c] := h_init(c)
__global__ void __launch_bounds__(256) scan_pass2(
    const float* __restrict__ sumdvB, const float* __restrict__ Alog,
    unsigned short* __restrict__ Hbuf){
  int gid = blockIdx.x*256 + threadIdx.x;   // b*8192 + d*16 + n
  float A = -__expf(Alog[gid & 8191]);
  float H = 0.f;
  #pragma unroll 4
  for (int c=0; c<CCH; c++){
    float s  = sumdvB[(size_t)c*(BATCH*DI) + (gid>>4)];
    size_t o = (size_t)c*SC + gid;
    float hf = bf2f(Hbuf[o]);
    Hbuf[o] = f2bf(H);
    H = __expf(A*s)*H + hf;
  }
}

// pass3: re-run chunk from h_init; y = C.h + D*u; gate with pre-silu'd z: g = y*zs
template<bool POW>
__device__ __forceinline__ void pass3_body(
    const unsigned short* dptr, unsigned short* uptr, const unsigned short* zptr,
    const float* Bls, const float* A, f32x2* h2, float Dd){
  #pragma unroll 2
  for (int l=0; l<CL; l++){
    float dv = bf2f(dptr[(size_t)l*512]);
    float uv = bf2f(uptr[(size_t)l*512]);
    float zs = bf2f(zptr[(size_t)l*1024]);   // already silu(z)
    const float* br = Bls + l*32;
    f32x4 B0 = *(const f32x4*)(br + 0);
    f32x4 B1 = *(const f32x4*)(br + 4);
    f32x4 B2 = *(const f32x4*)(br + 8);
    f32x4 B3 = *(const f32x4*)(br + 12);
    f32x4 C0 = *(const f32x4*)(br + 16);
    f32x4 C1 = *(const f32x4*)(br + 20);
    f32x4 C2 = *(const f32x4*)(br + 24);
    f32x4 C3 = *(const f32x4*)(br + 28);
    f32x2 b2[8] = {B0.xy, B0.zw, B1.xy, B1.zw, B2.xy, B2.zw, B3.xy, B3.zw};
    f32x2 c2[8] = {C0.xy, C0.zw, C1.xy, C1.zw, C2.xy, C2.zw, C3.xy, C3.zw};
    float t = dv*uv;
    f32x2 p0={0.f,0.f}, p1={0.f,0.f}, p2={0.f,0.f}, p3={0.f,0.f};
    if (POW){
      f32x2 ap2[8];
      powers16_pk(__expf(dv*A[0]), ap2);
      #pragma unroll
      for (int j=0;j<8;j++){
        h2[j] = ap2[j]*h2[j] + t*b2[j];
        f32x2 hp = h2[j]*c2[j];
        if ((j&3)==0) p0 += hp; else if ((j&3)==1) p1 += hp; else if ((j&3)==2) p2 += hp; else p3 += hp;
      }
    } else {
      #pragma unroll
      for (int j=0;j<8;j++){
        f32x2 a = f32x2{__expf(dv*A[2*j]), __expf(dv*A[2*j+1])};
        h2[j] = a*h2[j] + t*b2[j];
        f32x2 hp = h2[j]*c2[j];
        if ((j&3)==0) p0 += hp; else if ((j&3)==1) p1 += hp; else if ((j&3)==2) p2 += hp; else p3 += hp;
      }
    }
    f32x2 ps = (p0+p1) + (p2+p3);
    float y = ps.x + ps.y + Dd*uv;
    uptr[(size_t)l*512] = f2bf(y * zs);
  }
}

__global__ void __launch_bounds__(256) scan_pass3(
    const unsigned short* __restrict__ dlt, unsigned short* __restrict__ u,
    const unsigned short* __restrict__ xz, const float* __restrict__ xdb,
    const float* __restrict__ Alog, const float* __restrict__ Dp,
    const unsigned short* __restrict__ Hbuf){
  __shared__ float Bls[CL*32];
  int bid = blockIdx.x;
  int half = bid & 1;
  int c = (bid >> 1) & (CCH-1);
  int b = bid / (CCH*2);
  int wave = threadIdx.x >> 6, lane = threadIdx.x & 63;
  int d = half*256 + wave*64 + lane;
  size_t rowbase = (size_t)b*SEQ + (size_t)c*CL;
  *(f32x2*)&Bls[threadIdx.x*2] = *(const f32x2*)(xdb + rowbase*32 + threadIdx.x*2);
  const float* ar = Alog + d*16;
  f32x4 Aq0 = *(const f32x4*)(ar+0), Aq1 = *(const f32x4*)(ar+4);
  f32x4 Aq2 = *(const f32x4*)(ar+8), Aq3 = *(const f32x4*)(ar+12);
  float A[16];
  #pragma unroll
  for (int i=0;i<16;i++) A[i] = -__expf(ASEL(i));
  bool pw = true;
  #pragma unroll
  for (int i=1;i<16;i++) pw = pw && (fabsf(A[i] - (float)(i+1)*A[0]) <= 1e-3f*fabsf(A[i]));
  float Dd = Dp[d];
  size_t o = (size_t)(c*BATCH + b)*512 + d;
  const unsigned short* Hp = Hbuf + o*16;
  u16x8 ha = *(const u16x8*)(Hp+0);
  u16x8 hb = *(const u16x8*)(Hp+8);
  f32x2 h2[8];
  #pragma unroll
  for (int j=0;j<4;j++) h2[j]   = f32x2{bf2f(ha[2*j]), bf2f(ha[2*j+1])};
  #pragma unroll
  for (int j=0;j<4;j++) h2[4+j] = f32x2{bf2f(hb[2*j]), bf2f(hb[2*j+1])};
  const unsigned short* dptr = dlt + rowbase*512 + d;
  unsigned short*       uptr = u   + rowbase*512 + d;
  const unsigned short* zptr = xz  + rowbase*1024 + 512 + d;
  __syncthreads();
  if (pw) pass3_body<true >(dptr, uptr, zptr, Bls, A, h2, Dd);
  else    pass3_body<false>(dptr, uptr, zptr, Bls, A, h2, Dd);
}

extern "C" void kernel_launch(void* const* d_in, const int* in_sizes, int n_in,
                              void* d_out, int out_size, void* d_ws, size_t ws_size,
                              hipStream_t stream){
  (void)in_sizes; (void)n_in; (void)out_size; (void)ws_size;
  const float* x      = (const float*)d_in[0];
  const float* W_in   = (const float*)d_in[1];
  const float* conv_w = (const float*)d_in[2];
  const float* conv_b = (const float*)d_in[3];
  const float* W_x    = (const float*)d_in[4];
  const float* W_dt   = (const float*)d_in[5];
  const float* b_dt   = (const float*)d_in[6];
  const float* A_log  = (const float*)d_in[7];
  const float* Dp     = (const float*)d_in[8];
  const float* W_out  = (const float*)d_in[9];
  const float* ln_g   = (const float*)d_in[10];
  const float* ln_b   = (const float*)d_in[11];
  float* out = (float*)d_out;

  // workspace carve-up (~200 MB)
  char* p = (char*)d_ws;
  auto alloc = [&](size_t bytes)->char*{
    char* r = p; p += (bytes + 255) & ~(size_t)255; return r;
  };
  unsigned short* hbuf   = (unsigned short*)alloc((size_t)MROWS*DM*2);  // 16.8 MB residual bf16
  unsigned short* xzb    = (unsigned short*)alloc((size_t)MROWS*1024*2);// 67 MB
  unsigned short* ubuf   = (unsigned short*)alloc((size_t)MROWS*DI*2);  // 33.5 MB (u, then gated g)
  unsigned short* lnb    = (unsigned short*)alloc((size_t)MROWS*DI*2);  // 33.5 MB shared: lnb / delta
  unsigned short* dlt    = lnb;                                         // alias (disjoint live ranges)
  float*          xdbc   = (float*)alloc((size_t)MROWS*32*4);           // 4.2 MB (B,C)
  unsigned short* dtb    = (unsigned short*)alloc((size_t)MROWS*32*2);  // 2.1 MB dt bf16, K=32-padded
  unsigned short* WinB   = (unsigned short*)alloc((size_t)NL*1024*DM*2);// 3.1 MB
  unsigned short* WoutB  = (unsigned short*)alloc((size_t)NL*DM*DI*2);  // 1.6 MB
  unsigned short* WxB    = (unsigned short*)alloc((size_t)NL*48*DI*2);  // 0.3 MB
  unsigned short* WdtpB  = (unsigned short*)alloc((size_t)NL*DI*32*2);  // 0.2 MB
  float*          sumdvB = (float*)alloc((size_t)CCH*BATCH*DI*4);       // 4.2 MB
  unsigned short* Hbuf   = (unsigned short*)alloc((size_t)CCH*SC*2);    // 33.5 MB bf16

  // weight conversion
  {
    int n1 = NL*1024*DM;  cvt_bf16<<<(n1+255)/256, 256, 0, stream>>>(W_in,  WinB,  n1);
    int n3 = NL*DM*DI;    cvt_bf16<<<(n3+255)/256, 256, 0, stream>>>(W_out, WoutB, n3);
    int n2 = NL*48*DI;    cvt_bf16<<<(n2+255)/256, 256, 0, stream>>>(W_x,   WxB,   n2);
    wdtp_kernel<<<NL*DI*32/256, 256, 0, stream>>>(W_dt, WdtpB);
  }

  transpose_in<<<dim3(SEQ/32, DM/32, BATCH), dim3(32,8), 0, stream>>>(x, hbuf);

  for (int i=0; i<NL; i++){
    const unsigned short* Wi = WinB  + (size_t)i*1024*DM;
    const unsigned short* Wo = WoutB + (size_t)i*DM*DI;
    const unsigned short* Wx48 = WxB + (size_t)i*48*DI;
    const unsigned short* Wdp = WdtpB + (size_t)i*DI*32;
    const float* Al = A_log + (size_t)i*DI*DS;

    ln_kernel<<<MROWS/4, 256, 0, stream>>>(hbuf, ln_g + i*DM, ln_b + i*DM, lnb);

    // xz = ln @ W_in^T  [M,1024] bf16; z half stored as silu(z)
    gemm_big<1><<<dim3(1024/128, MROWS/256), 512, 0, stream>>>(lnb, Wi, xzb, nullptr, nullptr, 1024, DM);

    conv_kernel<<<MROWS*32/256, 256, 0, stream>>>(xzb, conv_w + (size_t)i*DI*4,
                                                  conv_b + i*DI, ubuf);

    // dt (bf16, K=32 padded) + B/C (f32): u @ Wx^T, N=48
    gemm_big<5><<<dim3(1, MROWS/256), 512, 0, stream>>>(ubuf, Wx48, dtb, xdbc, nullptr, 48, DI);

    // delta = softplus(dtb @ Wdtp^T + b_dt)  [M,512] bf16, K=32 (rank-16 factored)
    gemm_big<3><<<dim3(512/128, MROWS/256), 512, 0, stream>>>(dtb, Wdp, dlt, nullptr,
                                                              b_dt + i*DI, 512, 32);

    scan_pass1<<<BATCH*CCH*2, 256, 0, stream>>>(dlt, ubuf, xdbc, Al, sumdvB, Hbuf);
    scan_pass2<<<SC/256, 256, 0, stream>>>(sumdvB, Al, Hbuf);
    scan_pass3<<<BATCH*CCH*2, 256, 0, stream>>>(dlt, ubuf, xzb, xdbc, Al, Dp + i*DI, Hbuf);

    // h += g @ W_out^T  [M,256] bf16 RMW accumulate
    gemm_big<2><<<dim3(DM/128, MROWS/256), 512, 0, stream>>>(ubuf, Wo, hbuf, nullptr, nullptr, DM, DI);
  }

  transpose_out<<<dim3(SEQ/32, DM/32, BATCH), dim3(32,8), 0, stream>>>(hbuf, out);
}

// Round 19
// 1246.198 us; speedup vs baseline: 1.0675x; 1.0675x over previous
//
#include <hip/hip_runtime.h>

#define BATCH 8
#define SEQ   4096
#define DM    256
#define DI    512
#define DS    16
#define DTR   16
#define NL    6
#define MROWS (BATCH*SEQ)   // 32768
#define CCH   128           // scan chunks
#define CL    (SEQ/CCH)     // 32 steps per chunk
#define SC    (BATCH*DI*DS) // 65536 per-chunk scan states

typedef float  f32x4 __attribute__((ext_vector_type(4)));
typedef float  f32x2 __attribute__((ext_vector_type(2)));
typedef __bf16 bf16x8 __attribute__((ext_vector_type(8)));
typedef unsigned short u16x8 __attribute__((ext_vector_type(8)));
typedef unsigned short u16x4 __attribute__((ext_vector_type(4)));

__device__ __forceinline__ float bf2f(unsigned short b){
  unsigned u = ((unsigned)b) << 16;
  return __builtin_bit_cast(float, u);
}
__device__ __forceinline__ unsigned short f2bf(float f){
  unsigned u = __builtin_bit_cast(unsigned, f);
  unsigned r = u + 0x7FFFu + ((u >> 16) & 1u);
  return (unsigned short)(r >> 16);
}

#define ASEL(i) ((i)<4?Aq0[(i)&3]:(i)<8?Aq1[(i)&3]:(i)<12?Aq2[(i)&3]:Aq3[(i)&3])

// packed powers: ap2[j] = {a1^(2j+1), a1^(2j+2)}, j=0..7  (3 scalar + 7 pk muls)
__device__ __forceinline__ void powers16_pk(float a1, f32x2* ap2){
  float a2=a1*a1, a4=a2*a2, a8=a4*a4;
  ap2[0] = f32x2{a1, a2};
  ap2[1] = ap2[0]*a2;   // a3,a4
  ap2[2] = ap2[0]*a4;   // a5,a6
  ap2[3] = ap2[1]*a4;   // a7,a8
  ap2[4] = ap2[0]*a8;   // a9,a10
  ap2[5] = ap2[1]*a8;   // a11,a12
  ap2[6] = ap2[2]*a8;   // a13,a14
  ap2[7] = ap2[3]*a8;   // a15,a16
}

// ---------------- transpose x [B,256,L] f32 -> h [(b*L+l)*256+c] bf16 ----------------
__global__ void transpose_in(const float* __restrict__ x, unsigned short* __restrict__ h){
  __shared__ float tile[32][33];
  int b = blockIdx.z;
  int l0 = blockIdx.x*32, c0 = blockIdx.y*32;
  int tx = threadIdx.x, ty = threadIdx.y;
  #pragma unroll
  for (int i=0;i<4;i++)
    tile[ty+8*i][tx] = x[((size_t)(b*DM + c0+ty+8*i))*SEQ + l0 + tx];
  __syncthreads();
  #pragma unroll
  for (int i=0;i<4;i++)
    h[((size_t)(b*SEQ + l0+ty+8*i))*DM + c0 + tx] = f2bf(tile[tx][ty+8*i]);
}

// ---------------- transpose h (bf16) -> out [B,256,L] f32 ----------------
__global__ void transpose_out(const unsigned short* __restrict__ h, float* __restrict__ out){
  __shared__ float tile[32][33];
  int b = blockIdx.z;
  int l0 = blockIdx.x*32, c0 = blockIdx.y*32;
  int tx = threadIdx.x, ty = threadIdx.y;
  #pragma unroll
  for (int i=0;i<4;i++)
    tile[ty+8*i][tx] = bf2f(h[((size_t)(b*SEQ + l0+ty+8*i))*DM + c0 + tx]);
  __syncthreads();
  #pragma unroll
  for (int i=0;i<4;i++)
    out[((size_t)(b*DM + c0+ty+8*i))*SEQ + l0 + tx] = tile[tx][ty+8*i];
}

// ---------------- f32 -> bf16 convert ----------------
__global__ void cvt_bf16(const float* __restrict__ in, unsigned short* __restrict__ out, int n){
  int i = blockIdx.x*256 + threadIdx.x;
  if (i < n) out[i] = f2bf(in[i]);
}

// ------- W_dt padded to K=32 (cols 16..31 zero), bf16: Wdtp[l][512][32] -------
__global__ void wdtp_kernel(const float* __restrict__ Wdt, unsigned short* __restrict__ Wdtp){
  int idx = blockIdx.x*256 + threadIdx.x;   // over NL*512*32
  int l = idx >> 14;
  int r = idx & 16383;
  int d = r >> 5, k = r & 31;
  float v = (k < 16) ? Wdt[(size_t)l*DI*DTR + d*DTR + k] : 0.f;
  Wdtp[idx] = f2bf(v);
}

// ---------------- LayerNorm over 256 channels, one wave per row, bf16 in/out ----------------
__global__ void ln_kernel(const unsigned short* __restrict__ h, const float* __restrict__ g,
                          const float* __restrict__ bta, unsigned short* __restrict__ out){
  int wave = threadIdx.x >> 6, lane = threadIdx.x & 63;
  size_t row = (size_t)blockIdx.x*4 + wave;
  u16x4 hv = *reinterpret_cast<const u16x4*>(h + row*DM + lane*4);
  float v0 = bf2f(hv[0]), v1 = bf2f(hv[1]), v2 = bf2f(hv[2]), v3 = bf2f(hv[3]);
  float s  = v0 + v1 + v2 + v3;
  float sq = v0*v0 + v1*v1 + v2*v2 + v3*v3;
  #pragma unroll
  for (int off=32; off; off>>=1){
    s  += __shfl_xor(s,  off, 64);
    sq += __shfl_xor(sq, off, 64);
  }
  float mean = s * (1.f/DM);
  float var  = sq * (1.f/DM) - mean*mean;
  float rstd = rsqrtf(var + 1e-5f);
  f32x4 gg = *reinterpret_cast<const f32x4*>(g   + lane*4);
  f32x4 bb = *reinterpret_cast<const f32x4*>(bta + lane*4);
  unsigned short* o = out + row*DM + lane*4;
  u16x4 ov;
  ov[0] = f2bf((v0-mean)*rstd*gg.x + bb.x);
  ov[1] = f2bf((v1-mean)*rstd*gg.y + bb.y);
  ov[2] = f2bf((v2-mean)*rstd*gg.z + bb.z);
  ov[3] = f2bf((v3-mean)*rstd*gg.w + bb.w);
  *reinterpret_cast<u16x4*>(o) = ov;
}

// ======== 256x128-tile LDS double-buffered bf16 MFMA GEMM, 8 waves (64x64/wave) ========
// C[M,N] = A[M,K] @ W[N,K]^T. BK=32, dbuf, 2-barrier schedule. T1 XCD remap.
// MFMA operands SWAPPED (mfma(B,A)) so each lane's f32x4 = 4 consecutive N-cols of one
// row -> u16x4 / f32x4 vector stores in all epilogues.
// OUTMODE 1: bf16 store, silu for col >= N/2 (xz projection).
// OUTMODE 2: bf16 RMW accumulate (residual).
// OUTMODE 3: softplus(acc + bias[col]) bf16 store (delta; N==512, K==32).
// OUTMODE 5: split48 — col<16: bf16 dt -> Cout[row*32+col]; 16..31: f32 B -> Cout2 + zero-pad
//            Cout; 32..47: f32 C -> Cout2.
template<int OUTMODE>
__global__ __launch_bounds__(512) void gemm_big(const unsigned short* __restrict__ A,
                                                const unsigned short* __restrict__ W,
                                                void* __restrict__ Cout,
                                                float* __restrict__ Cout2,
                                                const float* __restrict__ bias, int N, int K){
  __shared__ __align__(16) unsigned short lds[2][12288];  // A: [0,8192) B: [8192,12288)
  unsigned nx = gridDim.x;
  unsigned L = blockIdx.x + nx*blockIdx.y;
  unsigned nwg = nx * gridDim.y;
  unsigned wid = (L & 7u) * (nwg >> 3) + (L >> 3);
  int bx = wid % nx, by = wid / nx;

  int tid  = threadIdx.x;
  int wave = tid >> 6, lane = tid & 63;
  int wr = wave >> 1, wc = wave & 1;
  int mblock = by*256, nblock = bx*128;
  int l15 = lane & 15;
  int g = lane >> 4;
  int rr = lane >> 2;
  int scol = ((lane&3) ^ (rr&3) ^ ((rr>>2)&3)) * 8;
  int rs = (g ^ (l15&3) ^ ((l15>>2)&3)) * 8;

  f32x4 acc[4][4] = {};

  auto stage = [&](int buf, int k0){
    #pragma unroll
    for (int j=0; j<2; j++){
      int st = wave*2 + j;                       // A stripes 0..15
      int rA = mblock + st*16 + rr;
      const unsigned short* ga = A + (size_t)rA*K + k0 + scol;
      __builtin_amdgcn_global_load_lds(ga, &lds[buf][st*512], 16, 0, 0);
    }
    {
      int st = wave;                             // B stripes 0..7
      int rB = nblock + st*16 + rr; if (rB >= N) rB = N-1;
      const unsigned short* gb = W + (size_t)rB*K + k0 + scol;
      __builtin_amdgcn_global_load_lds(gb, &lds[buf][8192 + st*512], 16, 0, 0);
    }
  };

  stage(0, 0);
  __syncthreads();

  int nsteps = K >> 5;
  for (int s=0; s<nsteps; s++){
    int buf = s & 1;
    if (s+1 < nsteps) stage(buf^1, (s+1)*32);
    bf16x8 af[4], bfr[4];
    #pragma unroll
    for (int mf=0; mf<4; mf++)
      af[mf] = *(const bf16x8*)&lds[buf][(wr*64 + mf*16 + l15)*32 + rs];
    #pragma unroll
    for (int nf=0; nf<4; nf++)
      bfr[nf] = *(const bf16x8*)&lds[buf][8192 + (wc*64 + nf*16 + l15)*32 + rs];
    #pragma unroll
    for (int mf=0; mf<4; mf++)
      #pragma unroll
      for (int nf=0; nf<4; nf++)
        acc[mf][nf] = __builtin_amdgcn_mfma_f32_16x16x32_bf16(bfr[nf], af[mf], acc[mf][nf], 0,0,0);
    __syncthreads();
  }

  // transposed-C epilogue: lane holds row = ...+l15, cols = ...+g*4+{0..3}
  int rowb = mblock + wr*64 + l15;
  int colb = nblock + wc*64 + g*4;
  #pragma unroll
  for (int mf=0; mf<4; mf++){
    int row = rowb + mf*16;
    #pragma unroll
    for (int nf=0; nf<4; nf++){
      int col = colb + nf*16;
      f32x4 v = acc[mf][nf];
      if (OUTMODE == 1){
        if (col >= (N>>1)){
          v.x = v.x / (1.f + __expf(-v.x)); v.y = v.y / (1.f + __expf(-v.y));
          v.z = v.z / (1.f + __expf(-v.z)); v.w = v.w / (1.f + __expf(-v.w));
        }
        u16x4 pk = {f2bf(v.x), f2bf(v.y), f2bf(v.z), f2bf(v.w)};
        *(u16x4*)((unsigned short*)Cout + (size_t)row*N + col) = pk;
      } else if (OUTMODE == 2){
        unsigned short* hp = (unsigned short*)Cout + (size_t)row*N + col;
        u16x4 old = *(const u16x4*)hp;
        u16x4 pk = {f2bf(bf2f(old[0]) + v.x), f2bf(bf2f(old[1]) + v.y),
                    f2bf(bf2f(old[2]) + v.z), f2bf(bf2f(old[3]) + v.w)};
        *(u16x4*)hp = pk;
      } else if (OUTMODE == 3){
        f32x4 b4 = *(const f32x4*)(bias + col);
        f32x4 t = v + b4;
        u16x4 pk;
        pk[0] = f2bf(fmaxf(t.x,0.f) + __logf(1.f + __expf(-fabsf(t.x))));
        pk[1] = f2bf(fmaxf(t.y,0.f) + __logf(1.f + __expf(-fabsf(t.y))));
        pk[2] = f2bf(fmaxf(t.z,0.f) + __logf(1.f + __expf(-fabsf(t.z))));
        pk[3] = f2bf(fmaxf(t.w,0.f) + __logf(1.f + __expf(-fabsf(t.w))));
        *(u16x4*)((unsigned short*)Cout + (size_t)row*N + col) = pk;
      } else { // OUTMODE 5
        if (col < 16){
          u16x4 pk = {f2bf(v.x), f2bf(v.y), f2bf(v.z), f2bf(v.w)};
          *(u16x4*)((unsigned short*)Cout + (size_t)row*32 + col) = pk;
        } else if (col < 48){
          *(f32x4*)(Cout2 + (size_t)row*32 + (col - 16)) = v;
          if (col < 32){
            u16x4 z = {0,0,0,0};
            *(u16x4*)((unsigned short*)Cout + (size_t)row*32 + col) = z;  // zero K-pad
          }
        }
      }
    }
  }
}

// ---------------- depthwise causal conv(4) + bias + SiLU, 8 channels x 2 rows/thread ----------------
__global__ void conv_kernel(const unsigned short* __restrict__ xz, const float* __restrict__ cw,
                            const float* __restrict__ cb, unsigned short* __restrict__ u){
  size_t idx = (size_t)blockIdx.x*256 + threadIdx.x;  // over MROWS/2 * 64
  int d0 = (int)(idx & 63) * 8;
  size_t row = (idx >> 6) * 2;
  int l = (int)(row & (SEQ-1));
  const unsigned short* base = xz + row*1024 + d0;
  u16x8 x0 = (l>=3) ? *(const u16x8*)(base - 3072) : (u16x8)(0);  // row-3
  u16x8 x1 = (l>=2) ? *(const u16x8*)(base - 2048) : (u16x8)(0);  // row-2
  u16x8 x2 = (l>=1) ? *(const u16x8*)(base - 1024) : (u16x8)(0);  // row-1
  u16x8 x3 = *(const u16x8*)(base);                               // row
  u16x8 x4 = *(const u16x8*)(base + 1024);                        // row+1 (same batch: row even)
  f32x4 cb0 = *reinterpret_cast<const f32x4*>(cb + d0);
  f32x4 cb1 = *reinterpret_cast<const f32x4*>(cb + d0 + 4);
  u16x8 o0, o1;
  #pragma unroll
  for (int j=0; j<8; j++){
    f32x4 w = *reinterpret_cast<const f32x4*>(cw + (d0+j)*4);
    float bj = (j<4) ? cb0[j] : cb1[j-4];
    float a0 = bj + bf2f(x0[j])*w.x + bf2f(x1[j])*w.y + bf2f(x2[j])*w.z + bf2f(x3[j])*w.w;
    float a1 = bj + bf2f(x1[j])*w.x + bf2f(x2[j])*w.y + bf2f(x3[j])*w.z + bf2f(x4[j])*w.w;
    o0[j] = f2bf(a0 / (1.f + __expf(-a0)));
    o1[j] = f2bf(a1 / (1.f + __expf(-a1)));
  }
  *(u16x8*)(u + row*512 + d0)       = o0;
  *(u16x8*)(u + (row+1)*512 + d0)   = o1;
}

// ================= SSM chunked scan, lane-per-d layout, packed f32x2 math =================
// B/C staged in LDS: Bls[l*32 + 0..15] = B, [16..31] = C
template<bool POW>
__device__ __forceinline__ void pass1_body(
    const unsigned short* dptr, const unsigned short* uptr, const float* Bls,
    const float* A, f32x2* h2, float& sumdv){
  #pragma unroll 2
  for (int l=0; l<CL; l++){
    float dv = bf2f(dptr[(size_t)l*512]);
    float uv = bf2f(uptr[(size_t)l*512]);
    const float* br = Bls + l*32;
    f32x4 B0 = *(const f32x4*)(br + 0);
    f32x4 B1 = *(const f32x4*)(br + 4);
    f32x4 B2 = *(const f32x4*)(br + 8);
    f32x4 B3 = *(const f32x4*)(br + 12);
    f32x2 b2[8] = {B0.xy, B0.zw, B1.xy, B1.zw, B2.xy, B2.zw, B3.xy, B3.zw};
    float t = dv*uv;
    sumdv += dv;
    if (POW){
      f32x2 ap2[8];
      powers16_pk(__expf(dv*A[0]), ap2);
      #pragma unroll
      for (int j=0;j<8;j++){ h2[j] = ap2[j]*h2[j] + t*b2[j]; }
    } else {
      #pragma unroll
      for (int j=0;j<8;j++){
        f32x2 a = f32x2{__expf(dv*A[2*j]), __expf(dv*A[2*j+1])};
        h2[j] = a*h2[j] + t*b2[j];
      }
    }
  }
}

__global__ void __launch_bounds__(256) scan_pass1(
    const unsigned short* __restrict__ dlt, const unsigned short* __restrict__ u,
    const float* __restrict__ xdb, const float* __restrict__ Alog,
    float* __restrict__ sumdvB, unsigned short* __restrict__ Hbuf){
  __shared__ float Bls[CL*32];
  int bid = blockIdx.x;               // ((b*CCH)+c)*2 + half
  int half = bid & 1;
  int c = (bid >> 1) & (CCH-1);
  int b = bid / (CCH*2);
  int wave = threadIdx.x >> 6, lane = threadIdx.x & 63;
  int d = half*256 + wave*64 + lane;
  size_t rowbase = (size_t)b*SEQ + (size_t)c*CL;
  // stage B/C: 32 rows x 32 f32 = 4KB, one f32x4 per thread
  *(f32x4*)&Bls[threadIdx.x*4] = *(const f32x4*)(xdb + rowbase*32 + threadIdx.x*4);
  const float* ar = Alog + d*16;
  f32x4 Aq0 = *(const f32x4*)(ar+0), Aq1 = *(const f32x4*)(ar+4);
  f32x4 Aq2 = *(const f32x4*)(ar+8), Aq3 = *(const f32x4*)(ar+12);
  float A[16];
  #pragma unroll
  for (int i=0;i<16;i++) A[i] = -__expf(ASEL(i));
  bool pw = true;
  #pragma unroll
  for (int i=1;i<16;i++) pw = pw && (fabsf(A[i] - (float)(i+1)*A[0]) <= 1e-3f*fabsf(A[i]));
  f32x2 h2[8];
  #pragma unroll
  for (int j=0;j<8;j++) h2[j] = f32x2{0.f,0.f};
  float sumdv = 0.f;
  const unsigned short* dptr = dlt + rowbase*512 + d;
  const unsigned short* uptr = u   + rowbase*512 + d;
  __syncthreads();
  if (pw) pass1_body<true >(dptr, uptr, Bls, A, h2, sumdv);
  else    pass1_body<false>(dptr, uptr, Bls, A, h2, sumdv);
  size_t o = (size_t)(c*BATCH + b)*512 + d;
  sumdvB[o] = sumdv;
  unsigned short* Hp = Hbuf + o*16;
  u16x8 ha, hb;
  #pragma unroll
  for (int j=0;j<4;j++){ ha[2*j] = f2bf(h2[j].x); ha[2*j+1] = f2bf(h2[j].y); }
  #pragma unroll
  for (int j=0;j<4;j++){ hb[2*j] = f2bf(h2[4+j].x); hb[2*j+1] = f2bf(h2[4+j].y); }
  *(u16x8*)(Hp+0) = ha;
  *(u16x8*)(Hp+8) = hb;
}

// pass2: thread per (b,d,n): serial combine over chunks; Hbuf[c] := h_init(c)
__global__ void __launch_bounds__(256) scan_pass2(
    const float* __restrict__ sumdvB, const float* __restrict__ Alog,
    unsigned short* __restrict__ Hbuf){
  int gid = blockIdx.x*256 + threadIdx.x;   // b*8192 + d*16 + n
  float A = -__expf(Alog[gid & 8191]);
  float H = 0.f;
  for (int c=0; c<CCH; c++){
    float s  = sumdvB[(size_t)c*(BATCH*DI) + (gid>>4)];
    size_t o = (size_t)c*SC + gid;
    float hf = bf2f(Hbuf[o]);
    Hbuf[o] = f2bf(H);
    H = __expf(A*s)*H + hf;
  }
}

// pass3: re-run chunk from h_init; y = C.h + D*u; gate with pre-silu'd z: g = y*zs
template<bool POW>
__device__ __forceinline__ void pass3_body(
    const unsigned short* dptr, unsigned short* uptr, const unsigned short* zptr,
    const float* Bls, const float* A, f32x2* h2, float Dd){
  #pragma unroll 2
  for (int l=0; l<CL; l++){
    float dv = bf2f(dptr[(size_t)l*512]);
    float uv = bf2f(uptr[(size_t)l*512]);
    float zs = bf2f(zptr[(size_t)l*1024]);   // already silu(z)
    const float* br = Bls + l*32;
    f32x4 B0 = *(const f32x4*)(br + 0);
    f32x4 B1 = *(const f32x4*)(br + 4);
    f32x4 B2 = *(const f32x4*)(br + 8);
    f32x4 B3 = *(const f32x4*)(br + 12);
    f32x4 C0 = *(const f32x4*)(br + 16);
    f32x4 C1 = *(const f32x4*)(br + 20);
    f32x4 C2 = *(const f32x4*)(br + 24);
    f32x4 C3 = *(const f32x4*)(br + 28);
    f32x2 b2[8] = {B0.xy, B0.zw, B1.xy, B1.zw, B2.xy, B2.zw, B3.xy, B3.zw};
    f32x2 c2[8] = {C0.xy, C0.zw, C1.xy, C1.zw, C2.xy, C2.zw, C3.xy, C3.zw};
    float t = dv*uv;
    f32x2 p0={0.f,0.f}, p1={0.f,0.f}, p2={0.f,0.f}, p3={0.f,0.f};
    if (POW){
      f32x2 ap2[8];
      powers16_pk(__expf(dv*A[0]), ap2);
      #pragma unroll
      for (int j=0;j<8;j++){
        h2[j] = ap2[j]*h2[j] + t*b2[j];
        f32x2 hp = h2[j]*c2[j];
        if ((j&3)==0) p0 += hp; else if ((j&3)==1) p1 += hp; else if ((j&3)==2) p2 += hp; else p3 += hp;
      }
    } else {
      #pragma unroll
      for (int j=0;j<8;j++){
        f32x2 a = f32x2{__expf(dv*A[2*j]), __expf(dv*A[2*j+1])};
        h2[j] = a*h2[j] + t*b2[j];
        f32x2 hp = h2[j]*c2[j];
        if ((j&3)==0) p0 += hp; else if ((j&3)==1) p1 += hp; else if ((j&3)==2) p2 += hp; else p3 += hp;
      }
    }
    f32x2 ps = (p0+p1) + (p2+p3);
    float y = ps.x + ps.y + Dd*uv;
    uptr[(size_t)l*512] = f2bf(y * zs);
  }
}

__global__ void __launch_bounds__(256) scan_pass3(
    const unsigned short* __restrict__ dlt, unsigned short* __restrict__ u,
    const unsigned short* __restrict__ xz, const float* __restrict__ xdb,
    const float* __restrict__ Alog, const float* __restrict__ Dp,
    const unsigned short* __restrict__ Hbuf){
  __shared__ float Bls[CL*32];
  int bid = blockIdx.x;
  int half = bid & 1;
  int c = (bid >> 1) & (CCH-1);
  int b = bid / (CCH*2);
  int wave = threadIdx.x >> 6, lane = threadIdx.x & 63;
  int d = half*256 + wave*64 + lane;
  size_t rowbase = (size_t)b*SEQ + (size_t)c*CL;
  *(f32x4*)&Bls[threadIdx.x*4] = *(const f32x4*)(xdb + rowbase*32 + threadIdx.x*4);
  const float* ar = Alog + d*16;
  f32x4 Aq0 = *(const f32x4*)(ar+0), Aq1 = *(const f32x4*)(ar+4);
  f32x4 Aq2 = *(const f32x4*)(ar+8), Aq3 = *(const f32x4*)(ar+12);
  float A[16];
  #pragma unroll
  for (int i=0;i<16;i++) A[i] = -__expf(ASEL(i));
  bool pw = true;
  #pragma unroll
  for (int i=1;i<16;i++) pw = pw && (fabsf(A[i] - (float)(i+1)*A[0]) <= 1e-3f*fabsf(A[i]));
  float Dd = Dp[d];
  size_t o = (size_t)(c*BATCH + b)*512 + d;
  const unsigned short* Hp = Hbuf + o*16;
  u16x8 ha = *(const u16x8*)(Hp+0);
  u16x8 hb = *(const u16x8*)(Hp+8);
  f32x2 h2[8];
  #pragma unroll
  for (int j=0;j<4;j++) h2[j]   = f32x2{bf2f(ha[2*j]), bf2f(ha[2*j+1])};
  #pragma unroll
  for (int j=0;j<4;j++) h2[4+j] = f32x2{bf2f(hb[2*j]), bf2f(hb[2*j+1])};
  const unsigned short* dptr = dlt + rowbase*512 + d;
  unsigned short*       uptr = u   + rowbase*512 + d;
  const unsigned short* zptr = xz  + rowbase*1024 + 512 + d;
  __syncthreads();
  if (pw) pass3_body<true >(dptr, uptr, zptr, Bls, A, h2, Dd);
  else    pass3_body<false>(dptr, uptr, zptr, Bls, A, h2, Dd);
}

extern "C" void kernel_launch(void* const* d_in, const int* in_sizes, int n_in,
                              void* d_out, int out_size, void* d_ws, size_t ws_size,
                              hipStream_t stream){
  (void)in_sizes; (void)n_in; (void)out_size; (void)ws_size;
  const float* x      = (const float*)d_in[0];
  const float* W_in   = (const float*)d_in[1];
  const float* conv_w = (const float*)d_in[2];
  const float* conv_b = (const float*)d_in[3];
  const float* W_x    = (const float*)d_in[4];
  const float* W_dt   = (const float*)d_in[5];
  const float* b_dt   = (const float*)d_in[6];
  const float* A_log  = (const float*)d_in[7];
  const float* Dp     = (const float*)d_in[8];
  const float* W_out  = (const float*)d_in[9];
  const float* ln_g   = (const float*)d_in[10];
  const float* ln_b   = (const float*)d_in[11];
  float* out = (float*)d_out;

  // workspace carve-up (~180 MB)
  char* p = (char*)d_ws;
  auto alloc = [&](size_t bytes)->char*{
    char* r = p; p += (bytes + 255) & ~(size_t)255; return r;
  };
  unsigned short* hbuf   = (unsigned short*)alloc((size_t)MROWS*DM*2);  // 16.8 MB residual bf16
  unsigned short* xzb    = (unsigned short*)alloc((size_t)MROWS*1024*2);// 67 MB
  unsigned short* ubuf   = (unsigned short*)alloc((size_t)MROWS*DI*2);  // 33.5 MB (u, then gated g)
  unsigned short* lnb    = (unsigned short*)alloc((size_t)MROWS*DI*2);  // 33.5 MB shared: lnb / delta
  unsigned short* dlt    = lnb;                                         // alias (disjoint live ranges)
  float*          xdbc   = (float*)alloc((size_t)MROWS*32*4);           // 4.2 MB (B,C)
  unsigned short* dtb    = (unsigned short*)alloc((size_t)MROWS*32*2);  // 2.1 MB dt bf16, K=32-padded
  unsigned short* WinB   = (unsigned short*)alloc((size_t)NL*1024*DM*2);// 3.1 MB
  unsigned short* WoutB  = (unsigned short*)alloc((size_t)NL*DM*DI*2);  // 1.6 MB
  unsigned short* WxB    = (unsigned short*)alloc((size_t)NL*48*DI*2);  // 0.3 MB
  unsigned short* WdtpB  = (unsigned short*)alloc((size_t)NL*DI*32*2);  // 0.2 MB
  float*          sumdvB = (float*)alloc((size_t)CCH*BATCH*DI*4);       // 2.1 MB
  unsigned short* Hbuf   = (unsigned short*)alloc((size_t)CCH*SC*2);    // 16.8 MB bf16

  // weight conversion
  {
    int n1 = NL*1024*DM;  cvt_bf16<<<(n1+255)/256, 256, 0, stream>>>(W_in,  WinB,  n1);
    int n3 = NL*DM*DI;    cvt_bf16<<<(n3+255)/256, 256, 0, stream>>>(W_out, WoutB, n3);
    int n2 = NL*48*DI;    cvt_bf16<<<(n2+255)/256, 256, 0, stream>>>(W_x,   WxB,   n2);
    wdtp_kernel<<<NL*DI*32/256, 256, 0, stream>>>(W_dt, WdtpB);
  }

  transpose_in<<<dim3(SEQ/32, DM/32, BATCH), dim3(32,8), 0, stream>>>(x, hbuf);

  for (int i=0; i<NL; i++){
    const unsigned short* Wi = WinB  + (size_t)i*1024*DM;
    const unsigned short* Wo = WoutB + (size_t)i*DM*DI;
    const unsigned short* Wx48 = WxB + (size_t)i*48*DI;
    const unsigned short* Wdp = WdtpB + (size_t)i*DI*32;
    const float* Al = A_log + (size_t)i*DI*DS;

    ln_kernel<<<MROWS/4, 256, 0, stream>>>(hbuf, ln_g + i*DM, ln_b + i*DM, lnb);

    // xz = ln @ W_in^T  [M,1024] bf16; z half stored as silu(z)
    gemm_big<1><<<dim3(1024/128, MROWS/256), 512, 0, stream>>>(lnb, Wi, xzb, nullptr, nullptr, 1024, DM);

    conv_kernel<<<MROWS*32/256, 256, 0, stream>>>(xzb, conv_w + (size_t)i*DI*4,
                                                  conv_b + i*DI, ubuf);

    // dt (bf16, K=32 padded) + B/C (f32): u @ Wx^T, N=48
    gemm_big<5><<<dim3(1, MROWS/256), 512, 0, stream>>>(ubuf, Wx48, dtb, xdbc, nullptr, 48, DI);

    // delta = softplus(dtb @ Wdtp^T + b_dt)  [M,512] bf16, K=32 (rank-16 factored)
    gemm_big<3><<<dim3(512/128, MROWS/256), 512, 0, stream>>>(dtb, Wdp, dlt, nullptr,
                                                              b_dt + i*DI, 512, 32);

    scan_pass1<<<BATCH*CCH*2, 256, 0, stream>>>(dlt, ubuf, xdbc, Al, sumdvB, Hbuf);
    scan_pass2<<<SC/256, 256, 0, stream>>>(sumdvB, Al, Hbuf);
    scan_pass3<<<BATCH*CCH*2, 256, 0, stream>>>(dlt, ubuf, xzb, xdbc, Al, Dp + i*DI, Hbuf);

    // h += g @ W_out^T  [M,256] bf16 RMW accumulate
    gemm_big<2><<<dim3(DM/128, MROWS/256), 512, 0, stream>>>(ubuf, Wo, hbuf, nullptr, nullptr, DM, DI);
  }

  transpose_out<<<dim3(SEQ/32, DM/32, BATCH), dim3(32,8), 0, stream>>>(hbuf, out);
}

// Round 20
// 1233.380 us; speedup vs baseline: 1.0786x; 1.0104x over previous
//
#include <hip/hip_runtime.h>

#define BATCH 8
#define SEQ   4096
#define DM    256
#define DI    512
#define DS    16
#define DTR   16
#define NL    6
#define MROWS (BATCH*SEQ)   // 32768
#define CCH   128           // scan chunks
#define CL    (SEQ/CCH)     // 32 steps per chunk
#define SC    (BATCH*DI*DS) // 65536 per-chunk scan states

typedef float  f32x4 __attribute__((ext_vector_type(4)));
typedef float  f32x2 __attribute__((ext_vector_type(2)));
typedef __bf16 bf16x8 __attribute__((ext_vector_type(8)));
typedef unsigned short u16x8 __attribute__((ext_vector_type(8)));
typedef unsigned short u16x4 __attribute__((ext_vector_type(4)));

__device__ __forceinline__ float bf2f(unsigned short b){
  unsigned u = ((unsigned)b) << 16;
  return __builtin_bit_cast(float, u);
}
__device__ __forceinline__ unsigned short f2bf(float f){
  unsigned u = __builtin_bit_cast(unsigned, f);
  unsigned r = u + 0x7FFFu + ((u >> 16) & 1u);
  return (unsigned short)(r >> 16);
}

#define ASEL(i) ((i)<4?Aq0[(i)&3]:(i)<8?Aq1[(i)&3]:(i)<12?Aq2[(i)&3]:Aq3[(i)&3])

// packed powers: ap2[j] = {a1^(2j+1), a1^(2j+2)}, j=0..7  (3 scalar + 7 pk muls)
__device__ __forceinline__ void powers16_pk(float a1, f32x2* ap2){
  float a2=a1*a1, a4=a2*a2, a8=a4*a4;
  ap2[0] = f32x2{a1, a2};
  ap2[1] = ap2[0]*a2;   // a3,a4
  ap2[2] = ap2[0]*a4;   // a5,a6
  ap2[3] = ap2[1]*a4;   // a7,a8
  ap2[4] = ap2[0]*a8;   // a9,a10
  ap2[5] = ap2[1]*a8;   // a11,a12
  ap2[6] = ap2[2]*a8;   // a13,a14
  ap2[7] = ap2[3]*a8;   // a15,a16
}

// ---------------- transpose x [B,256,L] f32 -> h [(b*L+l)*256+c] bf16 ----------------
__global__ void transpose_in(const float* __restrict__ x, unsigned short* __restrict__ h){
  __shared__ float tile[32][33];
  int b = blockIdx.z;
  int l0 = blockIdx.x*32, c0 = blockIdx.y*32;
  int tx = threadIdx.x, ty = threadIdx.y;
  #pragma unroll
  for (int i=0;i<4;i++)
    tile[ty+8*i][tx] = x[((size_t)(b*DM + c0+ty+8*i))*SEQ + l0 + tx];
  __syncthreads();
  #pragma unroll
  for (int i=0;i<4;i++)
    h[((size_t)(b*SEQ + l0+ty+8*i))*DM + c0 + tx] = f2bf(tile[tx][ty+8*i]);
}

// ---------------- transpose h (bf16) -> out [B,256,L] f32 ----------------
__global__ void transpose_out(const unsigned short* __restrict__ h, float* __restrict__ out){
  __shared__ float tile[32][33];
  int b = blockIdx.z;
  int l0 = blockIdx.x*32, c0 = blockIdx.y*32;
  int tx = threadIdx.x, ty = threadIdx.y;
  #pragma unroll
  for (int i=0;i<4;i++)
    tile[ty+8*i][tx] = bf2f(h[((size_t)(b*SEQ + l0+ty+8*i))*DM + c0 + tx]);
  __syncthreads();
  #pragma unroll
  for (int i=0;i<4;i++)
    out[((size_t)(b*DM + c0+ty+8*i))*SEQ + l0 + tx] = tile[tx][ty+8*i];
}

// ---------------- f32 -> bf16 convert ----------------
__global__ void cvt_bf16(const float* __restrict__ in, unsigned short* __restrict__ out, int n){
  int i = blockIdx.x*256 + threadIdx.x;
  if (i < n) out[i] = f2bf(in[i]);
}

// ------- W_dt padded to K=32 (cols 16..31 zero), bf16: Wdtp[l][512][32] -------
__global__ void wdtp_kernel(const float* __restrict__ Wdt, unsigned short* __restrict__ Wdtp){
  int idx = blockIdx.x*256 + threadIdx.x;   // over NL*512*32
  int l = idx >> 14;
  int r = idx & 16383;
  int d = r >> 5, k = r & 31;
  float v = (k < 16) ? Wdt[(size_t)l*DI*DTR + d*DTR + k] : 0.f;
  Wdtp[idx] = f2bf(v);
}

// ---------------- LayerNorm over 256 channels, one wave per row, bf16 in/out ----------------
__global__ void ln_kernel(const unsigned short* __restrict__ h, const float* __restrict__ g,
                          const float* __restrict__ bta, unsigned short* __restrict__ out){
  int wave = threadIdx.x >> 6, lane = threadIdx.x & 63;
  size_t row = (size_t)blockIdx.x*4 + wave;
  u16x4 hv = *reinterpret_cast<const u16x4*>(h + row*DM + lane*4);
  float v0 = bf2f(hv[0]), v1 = bf2f(hv[1]), v2 = bf2f(hv[2]), v3 = bf2f(hv[3]);
  float s  = v0 + v1 + v2 + v3;
  float sq = v0*v0 + v1*v1 + v2*v2 + v3*v3;
  #pragma unroll
  for (int off=32; off; off>>=1){
    s  += __shfl_xor(s,  off, 64);
    sq += __shfl_xor(sq, off, 64);
  }
  float mean = s * (1.f/DM);
  float var  = sq * (1.f/DM) - mean*mean;
  float rstd = rsqrtf(var + 1e-5f);
  f32x4 gg = *reinterpret_cast<const f32x4*>(g   + lane*4);
  f32x4 bb = *reinterpret_cast<const f32x4*>(bta + lane*4);
  unsigned short* o = out + row*DM + lane*4;
  u16x4 ov;
  ov[0] = f2bf((v0-mean)*rstd*gg.x + bb.x);
  ov[1] = f2bf((v1-mean)*rstd*gg.y + bb.y);
  ov[2] = f2bf((v2-mean)*rstd*gg.z + bb.z);
  ov[3] = f2bf((v3-mean)*rstd*gg.w + bb.w);
  *reinterpret_cast<u16x4*>(o) = ov;
}

// ======== 256x128-tile LDS double-buffered bf16 MFMA GEMM, 8 waves (64x64/wave) ========
// C[M,N] = A[M,K] @ W[N,K]^T. BK=32, dbuf, 2-barrier schedule. T1 XCD remap.
// MFMA operands SWAPPED (mfma(B,A)) so each lane's f32x4 = 4 consecutive N-cols of one
// row -> u16x4 / f32x4 vector stores in all epilogues.
// OUTMODE 1: bf16 store, silu for col >= N/2 (xz projection).
// OUTMODE 2: bf16 RMW accumulate (residual).
// OUTMODE 3: softplus(acc + bias[col]) bf16 store (delta; N==512, K==32).
// OUTMODE 5: split48 — col<16: bf16 dt -> Cout[row*32+col]; 16..31: f32 B -> Cout2 + zero-pad
//            Cout; 32..47: f32 C -> Cout2.
template<int OUTMODE>
__global__ __launch_bounds__(512) void gemm_big(const unsigned short* __restrict__ A,
                                                const unsigned short* __restrict__ W,
                                                void* __restrict__ Cout,
                                                float* __restrict__ Cout2,
                                                const float* __restrict__ bias, int N, int K){
  __shared__ __align__(16) unsigned short lds[2][12288];  // A: [0,8192) B: [8192,12288)
  unsigned nx = gridDim.x;
  unsigned L = blockIdx.x + nx*blockIdx.y;
  unsigned nwg = nx * gridDim.y;
  unsigned wid = (L & 7u) * (nwg >> 3) + (L >> 3);
  int bx = wid % nx, by = wid / nx;

  int tid  = threadIdx.x;
  int wave = tid >> 6, lane = tid & 63;
  int wr = wave >> 1, wc = wave & 1;
  int mblock = by*256, nblock = bx*128;
  int l15 = lane & 15;
  int g = lane >> 4;
  int rr = lane >> 2;
  int scol = ((lane&3) ^ (rr&3) ^ ((rr>>2)&3)) * 8;
  int rs = (g ^ (l15&3) ^ ((l15>>2)&3)) * 8;

  f32x4 acc[4][4] = {};

  auto stage = [&](int buf, int k0){
    #pragma unroll
    for (int j=0; j<2; j++){
      int st = wave*2 + j;                       // A stripes 0..15
      int rA = mblock + st*16 + rr;
      const unsigned short* ga = A + (size_t)rA*K + k0 + scol;
      __builtin_amdgcn_global_load_lds(ga, &lds[buf][st*512], 16, 0, 0);
    }
    {
      int st = wave;                             // B stripes 0..7
      int rB = nblock + st*16 + rr; if (rB >= N) rB = N-1;
      const unsigned short* gb = W + (size_t)rB*K + k0 + scol;
      __builtin_amdgcn_global_load_lds(gb, &lds[buf][8192 + st*512], 16, 0, 0);
    }
  };

  stage(0, 0);
  __syncthreads();

  int nsteps = K >> 5;
  for (int s=0; s<nsteps; s++){
    int buf = s & 1;
    if (s+1 < nsteps) stage(buf^1, (s+1)*32);
    bf16x8 af[4], bfr[4];
    #pragma unroll
    for (int mf=0; mf<4; mf++)
      af[mf] = *(const bf16x8*)&lds[buf][(wr*64 + mf*16 + l15)*32 + rs];
    #pragma unroll
    for (int nf=0; nf<4; nf++)
      bfr[nf] = *(const bf16x8*)&lds[buf][8192 + (wc*64 + nf*16 + l15)*32 + rs];
    #pragma unroll
    for (int mf=0; mf<4; mf++)
      #pragma unroll
      for (int nf=0; nf<4; nf++)
        acc[mf][nf] = __builtin_amdgcn_mfma_f32_16x16x32_bf16(bfr[nf], af[mf], acc[mf][nf], 0,0,0);
    __syncthreads();
  }

  // transposed-C epilogue: lane holds row = ...+l15, cols = ...+g*4+{0..3}
  int rowb = mblock + wr*64 + l15;
  int colb = nblock + wc*64 + g*4;
  #pragma unroll
  for (int mf=0; mf<4; mf++){
    int row = rowb + mf*16;
    #pragma unroll
    for (int nf=0; nf<4; nf++){
      int col = colb + nf*16;
      f32x4 v = acc[mf][nf];
      if (OUTMODE == 1){
        if (col >= (N>>1)){
          v.x = v.x / (1.f + __expf(-v.x)); v.y = v.y / (1.f + __expf(-v.y));
          v.z = v.z / (1.f + __expf(-v.z)); v.w = v.w / (1.f + __expf(-v.w));
        }
        u16x4 pk = {f2bf(v.x), f2bf(v.y), f2bf(v.z), f2bf(v.w)};
        *(u16x4*)((unsigned short*)Cout + (size_t)row*N + col) = pk;
      } else if (OUTMODE == 2){
        unsigned short* hp = (unsigned short*)Cout + (size_t)row*N + col;
        u16x4 old = *(const u16x4*)hp;
        u16x4 pk = {f2bf(bf2f(old[0]) + v.x), f2bf(bf2f(old[1]) + v.y),
                    f2bf(bf2f(old[2]) + v.z), f2bf(bf2f(old[3]) + v.w)};
        *(u16x4*)hp = pk;
      } else if (OUTMODE == 3){
        f32x4 b4 = *(const f32x4*)(bias + col);
        f32x4 t = v + b4;
        u16x4 pk;
        pk[0] = f2bf(fmaxf(t.x,0.f) + __logf(1.f + __expf(-fabsf(t.x))));
        pk[1] = f2bf(fmaxf(t.y,0.f) + __logf(1.f + __expf(-fabsf(t.y))));
        pk[2] = f2bf(fmaxf(t.z,0.f) + __logf(1.f + __expf(-fabsf(t.z))));
        pk[3] = f2bf(fmaxf(t.w,0.f) + __logf(1.f + __expf(-fabsf(t.w))));
        *(u16x4*)((unsigned short*)Cout + (size_t)row*N + col) = pk;
      } else { // OUTMODE 5
        if (col < 16){
          u16x4 pk = {f2bf(v.x), f2bf(v.y), f2bf(v.z), f2bf(v.w)};
          *(u16x4*)((unsigned short*)Cout + (size_t)row*32 + col) = pk;
        } else if (col < 48){
          *(f32x4*)(Cout2 + (size_t)row*32 + (col - 16)) = v;
          if (col < 32){
            u16x4 z = {0,0,0,0};
            *(u16x4*)((unsigned short*)Cout + (size_t)row*32 + col) = z;  // zero K-pad
          }
        }
      }
    }
  }
}

// ---------------- depthwise causal conv(4) + bias + SiLU, 8 channels x 4 rows/thread ----------------
__global__ void conv_kernel(const unsigned short* __restrict__ xz, const float* __restrict__ cw,
                            const float* __restrict__ cb, unsigned short* __restrict__ u){
  size_t idx = (size_t)blockIdx.x*256 + threadIdx.x;  // over MROWS/4 * 64
  int d0 = (int)(idx & 63) * 8;
  size_t row = (idx >> 6) * 4;
  int l = (int)(row & (SEQ-1));
  const unsigned short* base = xz + row*1024 + d0;
  u16x8 x0 = (l>=3) ? *(const u16x8*)(base - 3072) : (u16x8)(0);  // row-3
  u16x8 x1 = (l>=2) ? *(const u16x8*)(base - 2048) : (u16x8)(0);  // row-2
  u16x8 x2 = (l>=1) ? *(const u16x8*)(base - 1024) : (u16x8)(0);  // row-1
  u16x8 x3 = *(const u16x8*)(base);                               // row
  u16x8 x4 = *(const u16x8*)(base + 1024);                        // row+1
  u16x8 x5 = *(const u16x8*)(base + 2048);                        // row+2
  u16x8 x6 = *(const u16x8*)(base + 3072);                        // row+3 (same batch: row%4==0)
  f32x4 cb0 = *reinterpret_cast<const f32x4*>(cb + d0);
  f32x4 cb1 = *reinterpret_cast<const f32x4*>(cb + d0 + 4);
  u16x8 o0, o1, o2, o3;
  #pragma unroll
  for (int j=0; j<8; j++){
    f32x4 w = *reinterpret_cast<const f32x4*>(cw + (d0+j)*4);
    float bj = (j<4) ? cb0[j] : cb1[j-4];
    float v0 = bf2f(x0[j]), v1 = bf2f(x1[j]), v2 = bf2f(x2[j]), v3 = bf2f(x3[j]);
    float v4 = bf2f(x4[j]), v5 = bf2f(x5[j]), v6 = bf2f(x6[j]);
    float a0 = bj + v0*w.x + v1*w.y + v2*w.z + v3*w.w;
    float a1 = bj + v1*w.x + v2*w.y + v3*w.z + v4*w.w;
    float a2 = bj + v2*w.x + v3*w.y + v4*w.z + v5*w.w;
    float a3 = bj + v3*w.x + v4*w.y + v5*w.z + v6*w.w;
    o0[j] = f2bf(a0 / (1.f + __expf(-a0)));
    o1[j] = f2bf(a1 / (1.f + __expf(-a1)));
    o2[j] = f2bf(a2 / (1.f + __expf(-a2)));
    o3[j] = f2bf(a3 / (1.f + __expf(-a3)));
  }
  *(u16x8*)(u + row*512 + d0)       = o0;
  *(u16x8*)(u + (row+1)*512 + d0)   = o1;
  *(u16x8*)(u + (row+2)*512 + d0)   = o2;
  *(u16x8*)(u + (row+3)*512 + d0)   = o3;
}

// ================= SSM chunked scan, lane-per-d layout, packed f32x2 math =================
// B/C staged in LDS: Bls[l*32 + 0..15] = B, [16..31] = C
template<bool POW>
__device__ __forceinline__ void pass1_body(
    const unsigned short* dptr, const unsigned short* uptr, const float* Bls,
    const float* A, f32x2* h2, float& sumdv){
  #pragma unroll 2
  for (int l=0; l<CL; l++){
    float dv = bf2f(dptr[(size_t)l*512]);
    float uv = bf2f(uptr[(size_t)l*512]);
    const float* br = Bls + l*32;
    f32x4 B0 = *(const f32x4*)(br + 0);
    f32x4 B1 = *(const f32x4*)(br + 4);
    f32x4 B2 = *(const f32x4*)(br + 8);
    f32x4 B3 = *(const f32x4*)(br + 12);
    f32x2 b2[8] = {B0.xy, B0.zw, B1.xy, B1.zw, B2.xy, B2.zw, B3.xy, B3.zw};
    float t = dv*uv;
    sumdv += dv;
    if (POW){
      f32x2 ap2[8];
      powers16_pk(__expf(dv*A[0]), ap2);
      #pragma unroll
      for (int j=0;j<8;j++){ h2[j] = ap2[j]*h2[j] + t*b2[j]; }
    } else {
      #pragma unroll
      for (int j=0;j<8;j++){
        f32x2 a = f32x2{__expf(dv*A[2*j]), __expf(dv*A[2*j+1])};
        h2[j] = a*h2[j] + t*b2[j];
      }
    }
  }
}

__global__ void __launch_bounds__(256) scan_pass1(
    const unsigned short* __restrict__ dlt, const unsigned short* __restrict__ u,
    const float* __restrict__ xdb, const float* __restrict__ Alog,
    float* __restrict__ sumdvB, unsigned short* __restrict__ Hbuf){
  __shared__ float Bls[CL*32];
  int bid = blockIdx.x;               // ((b*CCH)+c)*2 + half
  int half = bid & 1;
  int c = (bid >> 1) & (CCH-1);
  int b = bid / (CCH*2);
  int wave = threadIdx.x >> 6, lane = threadIdx.x & 63;
  int d = half*256 + wave*64 + lane;
  size_t rowbase = (size_t)b*SEQ + (size_t)c*CL;
  // stage B/C: 32 rows x 32 f32 = 4KB, one f32x4 per thread
  *(f32x4*)&Bls[threadIdx.x*4] = *(const f32x4*)(xdb + rowbase*32 + threadIdx.x*4);
  const float* ar = Alog + d*16;
  f32x4 Aq0 = *(const f32x4*)(ar+0), Aq1 = *(const f32x4*)(ar+4);
  f32x4 Aq2 = *(const f32x4*)(ar+8), Aq3 = *(const f32x4*)(ar+12);
  float A[16];
  #pragma unroll
  for (int i=0;i<16;i++) A[i] = -__expf(ASEL(i));
  bool pw = true;
  #pragma unroll
  for (int i=1;i<16;i++) pw = pw && (fabsf(A[i] - (float)(i+1)*A[0]) <= 1e-3f*fabsf(A[i]));
  f32x2 h2[8];
  #pragma unroll
  for (int j=0;j<8;j++) h2[j] = f32x2{0.f,0.f};
  float sumdv = 0.f;
  const unsigned short* dptr = dlt + rowbase*512 + d;
  const unsigned short* uptr = u   + rowbase*512 + d;
  __syncthreads();
  if (pw) pass1_body<true >(dptr, uptr, Bls, A, h2, sumdv);
  else    pass1_body<false>(dptr, uptr, Bls, A, h2, sumdv);
  size_t o = (size_t)(c*BATCH + b)*512 + d;
  sumdvB[o] = sumdv;
  unsigned short* Hp = Hbuf + o*16;
  u16x8 ha, hb;
  #pragma unroll
  for (int j=0;j<4;j++){ ha[2*j] = f2bf(h2[j].x); ha[2*j+1] = f2bf(h2[j].y); }
  #pragma unroll
  for (int j=0;j<4;j++){ hb[2*j] = f2bf(h2[4+j].x); hb[2*j+1] = f2bf(h2[4+j].y); }
  *(u16x8*)(Hp+0) = ha;
  *(u16x8*)(Hp+8) = hb;
}

// pass2: thread per (b,d,n): serial combine over chunks; Hbuf[c] := h_init(c)
__global__ void __launch_bounds__(256) scan_pass2(
    const float* __restrict__ sumdvB, const float* __restrict__ Alog,
    unsigned short* __restrict__ Hbuf){
  int gid = blockIdx.x*256 + threadIdx.x;   // b*8192 + d*16 + n
  float A = -__expf(Alog[gid & 8191]);
  float H = 0.f;
  for (int c=0; c<CCH; c++){
    float s  = sumdvB[(size_t)c*(BATCH*DI) + (gid>>4)];
    size_t o = (size_t)c*SC + gid;
    float hf = bf2f(Hbuf[o]);
    Hbuf[o] = f2bf(H);
    H = __expf(A*s)*H + hf;
  }
}

// pass3: re-run chunk from h_init; y = C.h + D*u; gate with pre-silu'd z: g = y*zs
template<bool POW>
__device__ __forceinline__ void pass3_body(
    const unsigned short* dptr, unsigned short* uptr, const unsigned short* zptr,
    const float* Bls, const float* A, f32x2* h2, float Dd){
  #pragma unroll 2
  for (int l=0; l<CL; l++){
    float dv = bf2f(dptr[(size_t)l*512]);
    float uv = bf2f(uptr[(size_t)l*512]);
    float zs = bf2f(zptr[(size_t)l*1024]);   // already silu(z)
    const float* br = Bls + l*32;
    f32x4 B0 = *(const f32x4*)(br + 0);
    f32x4 B1 = *(const f32x4*)(br + 4);
    f32x4 B2 = *(const f32x4*)(br + 8);
    f32x4 B3 = *(const f32x4*)(br + 12);
    f32x4 C0 = *(const f32x4*)(br + 16);
    f32x4 C1 = *(const f32x4*)(br + 20);
    f32x4 C2 = *(const f32x4*)(br + 24);
    f32x4 C3 = *(const f32x4*)(br + 28);
    f32x2 b2[8] = {B0.xy, B0.zw, B1.xy, B1.zw, B2.xy, B2.zw, B3.xy, B3.zw};
    f32x2 c2[8] = {C0.xy, C0.zw, C1.xy, C1.zw, C2.xy, C2.zw, C3.xy, C3.zw};
    float t = dv*uv;
    f32x2 p0={0.f,0.f}, p1={0.f,0.f}, p2={0.f,0.f}, p3={0.f,0.f};
    if (POW){
      f32x2 ap2[8];
      powers16_pk(__expf(dv*A[0]), ap2);
      #pragma unroll
      for (int j=0;j<8;j++){
        h2[j] = ap2[j]*h2[j] + t*b2[j];
        f32x2 hp = h2[j]*c2[j];
        if ((j&3)==0) p0 += hp; else if ((j&3)==1) p1 += hp; else if ((j&3)==2) p2 += hp; else p3 += hp;
      }
    } else {
      #pragma unroll
      for (int j=0;j<8;j++){
        f32x2 a = f32x2{__expf(dv*A[2*j]), __expf(dv*A[2*j+1])};
        h2[j] = a*h2[j] + t*b2[j];
        f32x2 hp = h2[j]*c2[j];
        if ((j&3)==0) p0 += hp; else if ((j&3)==1) p1 += hp; else if ((j&3)==2) p2 += hp; else p3 += hp;
      }
    }
    f32x2 ps = (p0+p1) + (p2+p3);
    float y = ps.x + ps.y + Dd*uv;
    uptr[(size_t)l*512] = f2bf(y * zs);
  }
}

__global__ void __launch_bounds__(256) scan_pass3(
    const unsigned short* __restrict__ dlt, unsigned short* __restrict__ u,
    const unsigned short* __restrict__ xz, const float* __restrict__ xdb,
    const float* __restrict__ Alog, const float* __restrict__ Dp,
    const unsigned short* __restrict__ Hbuf){
  __shared__ float Bls[CL*32];
  int bid = blockIdx.x;
  int half = bid & 1;
  int c = (bid >> 1) & (CCH-1);
  int b = bid / (CCH*2);
  int wave = threadIdx.x >> 6, lane = threadIdx.x & 63;
  int d = half*256 + wave*64 + lane;
  size_t rowbase = (size_t)b*SEQ + (size_t)c*CL;
  *(f32x4*)&Bls[threadIdx.x*4] = *(const f32x4*)(xdb + rowbase*32 + threadIdx.x*4);
  const float* ar = Alog + d*16;
  f32x4 Aq0 = *(const f32x4*)(ar+0), Aq1 = *(const f32x4*)(ar+4);
  f32x4 Aq2 = *(const f32x4*)(ar+8), Aq3 = *(const f32x4*)(ar+12);
  float A[16];
  #pragma unroll
  for (int i=0;i<16;i++) A[i] = -__expf(ASEL(i));
  bool pw = true;
  #pragma unroll
  for (int i=1;i<16;i++) pw = pw && (fabsf(A[i] - (float)(i+1)*A[0]) <= 1e-3f*fabsf(A[i]));
  float Dd = Dp[d];
  size_t o = (size_t)(c*BATCH + b)*512 + d;
  const unsigned short* Hp = Hbuf + o*16;
  u16x8 ha = *(const u16x8*)(Hp+0);
  u16x8 hb = *(const u16x8*)(Hp+8);
  f32x2 h2[8];
  #pragma unroll
  for (int j=0;j<4;j++) h2[j]   = f32x2{bf2f(ha[2*j]), bf2f(ha[2*j+1])};
  #pragma unroll
  for (int j=0;j<4;j++) h2[4+j] = f32x2{bf2f(hb[2*j]), bf2f(hb[2*j+1])};
  const unsigned short* dptr = dlt + rowbase*512 + d;
  unsigned short*       uptr = u   + rowbase*512 + d;
  const unsigned short* zptr = xz  + rowbase*1024 + 512 + d;
  __syncthreads();
  if (pw) pass3_body<true >(dptr, uptr, zptr, Bls, A, h2, Dd);
  else    pass3_body<false>(dptr, uptr, zptr, Bls, A, h2, Dd);
}

extern "C" void kernel_launch(void* const* d_in, const int* in_sizes, int n_in,
                              void* d_out, int out_size, void* d_ws, size_t ws_size,
                              hipStream_t stream){
  (void)in_sizes; (void)n_in; (void)out_size; (void)ws_size;
  const float* x      = (const float*)d_in[0];
  const float* W_in   = (const float*)d_in[1];
  const float* conv_w = (const float*)d_in[2];
  const float* conv_b = (const float*)d_in[3];
  const float* W_x    = (const float*)d_in[4];
  const float* W_dt   = (const float*)d_in[5];
  const float* b_dt   = (const float*)d_in[6];
  const float* A_log  = (const float*)d_in[7];
  const float* Dp     = (const float*)d_in[8];
  const float* W_out  = (const float*)d_in[9];
  const float* ln_g   = (const float*)d_in[10];
  const float* ln_b   = (const float*)d_in[11];
  float* out = (float*)d_out;

  // workspace carve-up (~180 MB)
  char* p = (char*)d_ws;
  auto alloc = [&](size_t bytes)->char*{
    char* r = p; p += (bytes + 255) & ~(size_t)255; return r;
  };
  unsigned short* hbuf   = (unsigned short*)alloc((size_t)MROWS*DM*2);  // 16.8 MB residual bf16
  unsigned short* xzb    = (unsigned short*)alloc((size_t)MROWS*1024*2);// 67 MB
  unsigned short* ubuf   = (unsigned short*)alloc((size_t)MROWS*DI*2);  // 33.5 MB (u, then gated g)
  unsigned short* lnb    = (unsigned short*)alloc((size_t)MROWS*DI*2);  // 33.5 MB shared: lnb / delta
  unsigned short* dlt    = lnb;                                         // alias (disjoint live ranges)
  float*          xdbc   = (float*)alloc((size_t)MROWS*32*4);           // 4.2 MB (B,C)
  unsigned short* dtb    = (unsigned short*)alloc((size_t)MROWS*32*2);  // 2.1 MB dt bf16, K=32-padded
  unsigned short* WinB   = (unsigned short*)alloc((size_t)NL*1024*DM*2);// 3.1 MB
  unsigned short* WoutB  = (unsigned short*)alloc((size_t)NL*DM*DI*2);  // 1.6 MB
  unsigned short* WxB    = (unsigned short*)alloc((size_t)NL*48*DI*2);  // 0.3 MB
  unsigned short* WdtpB  = (unsigned short*)alloc((size_t)NL*DI*32*2);  // 0.2 MB
  float*          sumdvB = (float*)alloc((size_t)CCH*BATCH*DI*4);       // 2.1 MB
  unsigned short* Hbuf   = (unsigned short*)alloc((size_t)CCH*SC*2);    // 16.8 MB bf16

  // weight conversion
  {
    int n1 = NL*1024*DM;  cvt_bf16<<<(n1+255)/256, 256, 0, stream>>>(W_in,  WinB,  n1);
    int n3 = NL*DM*DI;    cvt_bf16<<<(n3+255)/256, 256, 0, stream>>>(W_out, WoutB, n3);
    int n2 = NL*48*DI;    cvt_bf16<<<(n2+255)/256, 256, 0, stream>>>(W_x,   WxB,   n2);
    wdtp_kernel<<<NL*DI*32/256, 256, 0, stream>>>(W_dt, WdtpB);
  }

  transpose_in<<<dim3(SEQ/32, DM/32, BATCH), dim3(32,8), 0, stream>>>(x, hbuf);

  for (int i=0; i<NL; i++){
    const unsigned short* Wi = WinB  + (size_t)i*1024*DM;
    const unsigned short* Wo = WoutB + (size_t)i*DM*DI;
    const unsigned short* Wx48 = WxB + (size_t)i*48*DI;
    const unsigned short* Wdp = WdtpB + (size_t)i*DI*32;
    const float* Al = A_log + (size_t)i*DI*DS;

    ln_kernel<<<MROWS/4, 256, 0, stream>>>(hbuf, ln_g + i*DM, ln_b + i*DM, lnb);

    // xz = ln @ W_in^T  [M,1024] bf16; z half stored as silu(z)
    gemm_big<1><<<dim3(1024/128, MROWS/256), 512, 0, stream>>>(lnb, Wi, xzb, nullptr, nullptr, 1024, DM);

    conv_kernel<<<MROWS*16/256, 256, 0, stream>>>(xzb, conv_w + (size_t)i*DI*4,
                                                  conv_b + i*DI, ubuf);

    // dt (bf16, K=32 padded) + B/C (f32): u @ Wx^T, N=48
    gemm_big<5><<<dim3(1, MROWS/256), 512, 0, stream>>>(ubuf, Wx48, dtb, xdbc, nullptr, 48, DI);

    // delta = softplus(dtb @ Wdtp^T + b_dt)  [M,512] bf16, K=32 (rank-16 factored)
    gemm_big<3><<<dim3(512/128, MROWS/256), 512, 0, stream>>>(dtb, Wdp, dlt, nullptr,
                                                              b_dt + i*DI, 512, 32);

    scan_pass1<<<BATCH*CCH*2, 256, 0, stream>>>(dlt, ubuf, xdbc, Al, sumdvB, Hbuf);
    scan_pass2<<<SC/256, 256, 0, stream>>>(sumdvB, Al, Hbuf);
    scan_pass3<<<BATCH*CCH*2, 256, 0, stream>>>(dlt, ubuf, xzb, xdbc, Al, Dp + i*DI, Hbuf);

    // h += g @ W_out^T  [M,256] bf16 RMW accumulate
    gemm_big<2><<<dim3(DM/128, MROWS/256), 512, 0, stream>>>(ubuf, Wo, hbuf, nullptr, nullptr, DM, DI);
  }

  transpose_out<<<dim3(SEQ/32, DM/32, BATCH), dim3(32,8), 0, stream>>>(hbuf, out);
}